// Round 1
// baseline (334.270 us; speedup 1.0000x reference)
//
#include <hip/hip_runtime.h>
#include <hip/hip_bf16.h>

typedef __attribute__((ext_vector_type(8))) short short8;
typedef __attribute__((ext_vector_type(4))) float floatx4;

#define MFMA16x32(a,b,c) __builtin_amdgcn_mfma_f32_16x16x32_bf16((a),(b),(c),0,0,0)

static __device__ __forceinline__ unsigned short f2b(float f) {
  __hip_bfloat16 h = __float2bfloat16(f);
  return __builtin_bit_cast(unsigned short, h);
}
static __device__ __forceinline__ float b2f(unsigned short u) {
  __hip_bfloat16 h = __builtin_bit_cast(__hip_bfloat16, u);
  return __bfloat162float(h);
}

#define HH 192
#define WWID 192
#define HW (192*192)
#define NB 8

// ---- ws layout (bytes) ----
#define Y_OFF    0                      // y = x + attn_out, NHWC bf16: 8*36864*96*2 = 56623104
#define H1_OFF   56623104               // h1 NHWC bf16: 56623104
#define AB_OFF   113246208              // attn_bias f32 64*64*4 = 16384
#define QKVW_OFF 113262592              // qkv_w bf16 192*96*2 = 36864
#define OUTW_OFF 113299456              // out_w bf16 96*64*2 = 12288
#define W1_OFF   113311744              // conv1_w bf16 96*96*2 = 18432
#define W2R_OFF  113330176              // conv2_w reordered bf16 96*864*2 = 165888
// total = 113496064 bytes

// =====================================================================
// prep: attn bias projection + bf16 weight repacks
// =====================================================================
__global__ __launch_bounds__(256) void k_prep(
    const float* __restrict__ bias, const float* __restrict__ bpw,
    const float* __restrict__ qkv_w, const float* __restrict__ out_w,
    const float* __restrict__ w1, const float* __restrict__ w2,
    char* __restrict__ ws) {
  int tid = blockIdx.x * blockDim.x + threadIdx.x;
  int nth = gridDim.x * blockDim.x;
  float* ab = (float*)(ws + AB_OFF);
  unsigned short* qkvw = (unsigned short*)(ws + QKVW_OFF);
  unsigned short* outw = (unsigned short*)(ws + OUTW_OFF);
  unsigned short* w1b  = (unsigned short*)(ws + W1_OFF);
  unsigned short* w2r  = (unsigned short*)(ws + W2R_OFF);

  for (int i = tid; i < 4096; i += nth) {
    float s = 0.f;
    #pragma unroll 8
    for (int k = 0; k < 64; k++) s += bias[k] * bpw[i*64 + k];
    ab[i] = s;
  }
  for (int i = tid; i < 192*96; i += nth) qkvw[i] = f2b(qkv_w[i]);
  for (int i = tid; i < 96*64;  i += nth) outw[i] = f2b(out_w[i]);
  for (int i = tid; i < 96*96;  i += nth) w1b[i]  = f2b(w1[i]);
  for (int i = tid; i < 96*864; i += nth) {
    int o = i / 864, k = i % 864;
    int tap = k / 96, c = k % 96;
    w2r[i] = f2b(w2[(o*96 + c)*9 + tap]);   // (O,C,3,3) -> [o][tap*96+c]
  }
}

// =====================================================================
// window attention: 1 block per 8x8 window, 256 threads (4 waves)
// =====================================================================
#define XW_S  104   // [64][104] bf16
#define QKV_S 200   // [64][200] bf16
#define P_S   72    // [4][64][72] bf16 ; o64 [64][72]
#define YB_S  101   // [64][101] f32

__global__ __launch_bounds__(256,2) void k_attn(
    const float* __restrict__ x, const float* __restrict__ qkv_b,
    const float* __restrict__ out_b, const char* __restrict__ wsr,
    unsigned short* __restrict__ y) {
  __shared__ __align__(16) char smem[71680];
  unsigned short* xw   = (unsigned short*)smem;            // dies after qkv GEMM
  unsigned short* p4   = (unsigned short*)smem;            // lives scores..PV
  float*          ybuf = (float*)smem;                     // lives proj..end
  unsigned short* qkvs = (unsigned short*)(smem + 36864);  // [64][200]
  unsigned short* o64  = (unsigned short*)(smem + 62464);  // [64][72]

  const float* ab = (const float*)(wsr + AB_OFF);
  const unsigned short* qkvw = (const unsigned short*)(wsr + QKVW_OFF);
  const unsigned short* outw = (const unsigned short*)(wsr + OUTW_OFF);

  int blk = blockIdx.x;
  int b = blk / 576, rem = blk % 576;
  int wi = rem / 24, wj = rem % 24;
  int h0 = wi * 8, w0 = wj * 8;
  const float* xb = x + (size_t)b * 96 * HW;

  int tid = threadIdx.x;
  int wv = tid >> 6, ln = tid & 63;
  int row = ln & 15, kg = ln >> 4;

  const floatx4 zf = {0.f, 0.f, 0.f, 0.f};
  const short8 zs = {0,0,0,0,0,0,0,0};

  // phase 1: x window -> LDS bf16 [t][c]
  for (int f = tid; f < 6144; f += 256) {
    int t = f & 63, c = f >> 6;
    float v = xb[c*HW + (h0 + (t>>3))*WWID + w0 + (t&7)];
    xw[t*XW_S + c] = f2b(v);
  }
  __syncthreads();

  // phase 2: qkv GEMM, wave wv covers j = wv*48 .. +47
  floatx4 accq[4][3];
  #pragma unroll
  for (int m = 0; m < 4; m++)
    #pragma unroll
    for (int n = 0; n < 3; n++) accq[m][n] = zf;
  #pragma unroll
  for (int ks = 0; ks < 3; ks++) {
    int c0 = ks*32 + kg*8;
    short8 a[4], bb[3];
    #pragma unroll
    for (int m = 0; m < 4; m++) a[m] = *(const short8*)&xw[(m*16+row)*XW_S + c0];
    #pragma unroll
    for (int n = 0; n < 3; n++) bb[n] = *(const short8*)&qkvw[(wv*48 + n*16 + row)*96 + c0];
    #pragma unroll
    for (int m = 0; m < 4; m++)
      #pragma unroll
      for (int n = 0; n < 3; n++) accq[m][n] = MFMA16x32(a[m], bb[n], accq[m][n]);
  }
  #pragma unroll
  for (int m = 0; m < 4; m++)
    #pragma unroll
    for (int n = 0; n < 3; n++) {
      int j = wv*48 + n*16 + row;
      float bj = qkv_b[j];
      #pragma unroll
      for (int r = 0; r < 4; r++) {
        int t = m*16 + kg*4 + r;
        qkvs[t*QKV_S + j] = f2b(accq[m][n][r] + bj);
      }
    }
  __syncthreads();   // also guarantees xw dead before p4 writes

  // phase 3: scores + softmax + PV, head h = wv
  int h = wv;
  floatx4 sc[4][4];
  {
    short8 qa[4], kb[4];
    if (kg < 2) {
      #pragma unroll
      for (int m = 0; m < 4; m++) qa[m] = *(const short8*)&qkvs[(m*16+row)*QKV_S + h*16 + kg*8];
      #pragma unroll
      for (int n = 0; n < 4; n++) kb[n] = *(const short8*)&qkvs[(n*16+row)*QKV_S + 64 + h*16 + kg*8];
    } else {
      #pragma unroll
      for (int m = 0; m < 4; m++) qa[m] = zs;
      #pragma unroll
      for (int n = 0; n < 4; n++) kb[n] = zs;
    }
    #pragma unroll
    for (int m = 0; m < 4; m++)
      #pragma unroll
      for (int n = 0; n < 4; n++) sc[m][n] = MFMA16x32(qa[m], kb[n], zf);
  }
  #pragma unroll
  for (int m = 0; m < 4; m++) {
    #pragma unroll
    for (int r = 0; r < 4; r++) {
      int t = m*16 + kg*4 + r;
      float v[4];
      #pragma unroll
      for (int n = 0; n < 4; n++)
        v[n] = sc[m][n][r]*0.25f + ab[t*64 + n*16 + row];
      float mx = fmaxf(fmaxf(v[0],v[1]), fmaxf(v[2],v[3]));
      #pragma unroll
      for (int d = 1; d < 16; d <<= 1) mx = fmaxf(mx, __shfl_xor(mx, d, 64));
      float sum = 0.f;
      #pragma unroll
      for (int n = 0; n < 4; n++) { v[n] = __expf(v[n]-mx); sum += v[n]; }
      #pragma unroll
      for (int d = 1; d < 16; d <<= 1) sum += __shfl_xor(sum, d, 64);
      float inv = 1.f / sum;
      #pragma unroll
      for (int n = 0; n < 4; n++)
        p4[(h*64 + t)*P_S + n*16 + row] = f2b(v[n]*inv);
    }
  }
  floatx4 ov[4];
  #pragma unroll
  for (int m = 0; m < 4; m++) ov[m] = zf;
  #pragma unroll
  for (int ks = 0; ks < 2; ks++) {
    short8 pa[4];
    #pragma unroll
    for (int m = 0; m < 4; m++)
      pa[m] = *(const short8*)&p4[(h*64 + m*16 + row)*P_S + ks*32 + kg*8];
    short8 vb = zs;
    #pragma unroll
    for (int i = 0; i < 8; i++)
      vb[i] = (short)qkvs[(ks*32 + kg*8 + i)*QKV_S + 128 + h*16 + row];
    #pragma unroll
    for (int m = 0; m < 4; m++) ov[m] = MFMA16x32(pa[m], vb, ov[m]);
  }
  #pragma unroll
  for (int m = 0; m < 4; m++)
    #pragma unroll
    for (int r = 0; r < 4; r++)
      o64[(m*16 + kg*4 + r)*P_S + h*16 + row] = f2b(ov[m][r]);
  __syncthreads();   // o64 complete; p4 dead -> ybuf may be written

  // phase 4: out projection, wave wv owns t-tile wv
  floatx4 op[6];
  #pragma unroll
  for (int n = 0; n < 6; n++) op[n] = zf;
  #pragma unroll
  for (int ks = 0; ks < 2; ks++) {
    short8 ao = *(const short8*)&o64[(wv*16 + row)*P_S + ks*32 + kg*8];
    #pragma unroll
    for (int n = 0; n < 6; n++) {
      short8 bo = *(const short8*)&outw[(n*16 + row)*64 + ks*32 + kg*8];
      op[n] = MFMA16x32(ao, bo, op[n]);
    }
  }
  #pragma unroll
  for (int n = 0; n < 6; n++) {
    float ob = out_b[n*16 + row];
    #pragma unroll
    for (int r = 0; r < 4; r++) {
      int t = wv*16 + kg*4 + r;
      ybuf[t*YB_S + n*16 + row] = op[n][r] + ob;
    }
  }
  __syncthreads();

  // phase 5: add x (coalesced along w), then write y NHWC bf16 (coalesced along c)
  for (int f = tid; f < 6144; f += 256) {
    int t = f & 63, c = f >> 6;
    ybuf[t*YB_S + c] += xb[c*HW + (h0 + (t>>3))*WWID + w0 + (t&7)];
  }
  __syncthreads();
  for (int f = tid; f < 6144; f += 256) {
    int c = f % 96, t = f / 96;
    int gi = h0 + (t>>3), gj = w0 + (t&7);
    y[((size_t)b*HW + gi*WWID + gj)*96 + c] = f2b(ybuf[t*YB_S + c]);
  }
}

// =====================================================================
// conv1 1x1 + leaky: GEMM straight from y NHWC, no LDS.
// 1 block = 64 contiguous pixels in one row. grid 8*192*3 = 4608
// =====================================================================
__global__ __launch_bounds__(256,2) void k_conv1(
    const unsigned short* __restrict__ y, const float* __restrict__ b1,
    const char* __restrict__ wsr, unsigned short* __restrict__ h1) {
  const unsigned short* w1b = (const unsigned short*)(wsr + W1_OFF);
  int blk = blockIdx.x;
  int b = blk / 576, rem = blk % 576;
  int i = rem / 3, j0 = (rem % 3) * 64;
  int tid = threadIdx.x;
  int wv = tid >> 6, ln = tid & 63;
  int row = ln & 15, kg = ln >> 4;
  const unsigned short* yb = y + ((size_t)b*HW + i*WWID + j0) * 96;
  unsigned short* hb = h1 + ((size_t)b*HW + i*WWID + j0) * 96;

  const floatx4 zf = {0.f, 0.f, 0.f, 0.f};
  floatx4 acc[6];
  #pragma unroll
  for (int n = 0; n < 6; n++) acc[n] = zf;
  #pragma unroll
  for (int ks = 0; ks < 3; ks++) {
    int c0 = ks*32 + kg*8;
    short8 a = *(const short8*)&yb[(wv*16 + row)*96 + c0];
    #pragma unroll
    for (int n = 0; n < 6; n++) {
      short8 bw = *(const short8*)&w1b[(n*16 + row)*96 + c0];
      acc[n] = MFMA16x32(a, bw, acc[n]);
    }
  }
  #pragma unroll
  for (int n = 0; n < 6; n++) {
    int o = n*16 + row;
    float bo = b1[o];
    #pragma unroll
    for (int r = 0; r < 4; r++) {
      int p = wv*16 + kg*4 + r;
      float v = acc[n][r] + bo;
      v = v >= 0.f ? v : 0.1f*v;
      hb[p*96 + o] = f2b(v);
    }
  }
}

// =====================================================================
// conv2 3x3 replicate-pad + leaky + residual. Implicit GEMM.
// 1 block = 8x32 spatial tile, all 96 out-ch. 512 threads (8 waves: 2 og x 4 pg)
// grid 8*24*6 = 1152
// =====================================================================
__global__ __launch_bounds__(512,4) void k_conv2(
    const unsigned short* __restrict__ h1, const unsigned short* __restrict__ y,
    const float* __restrict__ b2, const char* __restrict__ wsr,
    float* __restrict__ out) {
  __shared__ __align__(16) unsigned short h1t[340*104];   // 10x34 halo x 96ch (pad 104)
  const unsigned short* w2r = (const unsigned short*)(wsr + W2R_OFF);
  int blk = blockIdx.x;
  int b = blk / 144, rem = blk % 144;
  int i0 = (rem / 6) * 8, j0 = (rem % 6) * 32;
  int tid = threadIdx.x;

  // stage h1 tile with replicate-clamped halo
  for (int idx = tid; idx < 4080; idx += 512) {
    int pix = idx / 12, cc = (idx % 12) * 8;
    int hr = pix / 34, hc = pix % 34;
    int gi = min(max(i0 + hr - 1, 0), 191);
    int gj = min(max(j0 + hc - 1, 0), 191);
    *(short8*)&h1t[pix*104 + cc] =
        *(const short8*)&h1[((size_t)b*HW + gi*WWID + gj)*96 + cc];
  }
  __syncthreads();

  int wv = tid >> 6, ln = tid & 63;
  int row = ln & 15, kg = ln >> 4;
  int og = wv >> 2, pg = wv & 3;

  const floatx4 zf = {0.f, 0.f, 0.f, 0.f};
  floatx4 acc[3][4];
  #pragma unroll
  for (int m = 0; m < 3; m++)
    #pragma unroll
    for (int n = 0; n < 4; n++) acc[m][n] = zf;

  for (int s = 0; s < 27; s++) {
    int tap = s / 3, c0 = (s % 3) * 32;
    int di = tap / 3, dj = tap % 3;
    short8 a[3], bb[4];
    #pragma unroll
    for (int m = 0; m < 3; m++)
      a[m] = *(const short8*)&w2r[(og*48 + m*16 + row)*864 + s*32 + kg*8];
    #pragma unroll
    for (int n = 0; n < 4; n++) {
      int p = pg*64 + n*16 + row;
      int pr = p >> 5, pc = p & 31;
      bb[n] = *(const short8*)&h1t[((pr + di)*34 + pc + dj)*104 + c0 + kg*8];
    }
    #pragma unroll
    for (int m = 0; m < 3; m++)
      #pragma unroll
      for (int n = 0; n < 4; n++)
        acc[m][n] = MFMA16x32(a[m], bb[n], acc[m][n]);
  }

  // epilogue: leaky(acc + b2) + y residual -> out NCHW fp32
  #pragma unroll
  for (int m = 0; m < 3; m++) {
    #pragma unroll
    for (int r = 0; r < 4; r++) {
      int o = og*48 + m*16 + kg*4 + r;
      float bo = b2[o];
      #pragma unroll
      for (int n = 0; n < 4; n++) {
        int p = pg*64 + n*16 + row;
        int pr = p >> 5, pc = p & 31;
        float hv = acc[m][n][r] + bo;
        hv = hv >= 0.f ? hv : 0.1f*hv;
        float yv = b2f(y[((size_t)b*HW + (i0+pr)*WWID + j0+pc)*96 + o]);
        out[((size_t)(b*96 + o)*HH + i0 + pr)*WWID + j0 + pc] = yv + hv;
      }
    }
  }
}

// =====================================================================
extern "C" void kernel_launch(void* const* d_in, const int* in_sizes, int n_in,
                              void* d_out, int out_size, void* d_ws, size_t ws_size,
                              hipStream_t stream) {
  const float* x    = (const float*)d_in[0];
  const float* bias = (const float*)d_in[1];
  const float* bpw  = (const float*)d_in[2];
  const float* qkvw = (const float*)d_in[3];
  const float* qkvb = (const float*)d_in[4];
  const float* outw = (const float*)d_in[5];
  const float* outb = (const float*)d_in[6];
  const float* w1   = (const float*)d_in[7];
  const float* b1   = (const float*)d_in[8];
  const float* w2   = (const float*)d_in[9];
  const float* b2   = (const float*)d_in[10];

  char* ws = (char*)d_ws;
  float* out = (float*)d_out;
  unsigned short* y  = (unsigned short*)(ws + Y_OFF);
  unsigned short* h1 = (unsigned short*)(ws + H1_OFF);

  k_prep<<<128, 256, 0, stream>>>(bias, bpw, qkvw, outw, w1, w2, ws);
  k_attn<<<4608, 256, 0, stream>>>(x, qkvb, outb, ws, y);
  k_conv1<<<4608, 256, 0, stream>>>(y, b1, ws, h1);
  k_conv2<<<1152, 512, 0, stream>>>(h1, y, b2, ws, out);
}

// Round 3
// 293.954 us; speedup vs baseline: 1.1371x; 1.1371x over previous
//
#include <hip/hip_runtime.h>
#include <hip/hip_bf16.h>

typedef __attribute__((ext_vector_type(8))) short short8;
typedef __attribute__((ext_vector_type(4))) float floatx4;

#define MFMA16x32(a,b,c) __builtin_amdgcn_mfma_f32_16x16x32_bf16((a),(b),(c),0,0,0)

static __device__ __forceinline__ unsigned short f2b(float f) {
  __hip_bfloat16 h = __float2bfloat16(f);
  return __builtin_bit_cast(unsigned short, h);
}
static __device__ __forceinline__ float b2f(unsigned short u) {
  __hip_bfloat16 h = __builtin_bit_cast(__hip_bfloat16, u);
  return __bfloat162float(h);
}

#define HH 192
#define WWID 192
#define HW (192*192)

// ---- ws layout (bytes) ----
#define Y_OFF    0                      // y = x + attn_out, NHWC bf16: 56623104
#define H1_OFF   56623104               // h1 NHWC bf16 (conv1 out) -- SHARED with xt:
#define XT_OFF   56623104               //   xt (x as NHWC bf16) dead before conv1 writes h1
#define AB_OFF   113246208              // attn_bias f32 64*64*4
#define QKVW_OFF 113262592              // qkv_w bf16 192*96
#define OUTW_OFF 113299456              // out_w bf16 96*64
#define W1_OFF   113311744              // conv1_w bf16 96*96
#define W2R_OFF  113330176              // conv2_w reordered bf16 96*864
// total = 113496064 bytes

// =====================================================================
// prep: attn bias projection + bf16 weight repacks
// =====================================================================
__global__ __launch_bounds__(256) void k_prep(
    const float* __restrict__ bias, const float* __restrict__ bpw,
    const float* __restrict__ qkv_w, const float* __restrict__ out_w,
    const float* __restrict__ w1, const float* __restrict__ w2,
    char* __restrict__ ws) {
  int tid = blockIdx.x * blockDim.x + threadIdx.x;
  int nth = gridDim.x * blockDim.x;
  float* ab = (float*)(ws + AB_OFF);
  unsigned short* qkvw = (unsigned short*)(ws + QKVW_OFF);
  unsigned short* outw = (unsigned short*)(ws + OUTW_OFF);
  unsigned short* w1b  = (unsigned short*)(ws + W1_OFF);
  unsigned short* w2r  = (unsigned short*)(ws + W2R_OFF);

  for (int i = tid; i < 4096; i += nth) {
    float s = 0.f;
    #pragma unroll 8
    for (int k = 0; k < 64; k++) s += bias[k] * bpw[i*64 + k];
    ab[i] = s;
  }
  for (int i = tid; i < 192*96; i += nth) qkvw[i] = f2b(qkv_w[i]);
  for (int i = tid; i < 96*64;  i += nth) outw[i] = f2b(out_w[i]);
  for (int i = tid; i < 96*96;  i += nth) w1b[i]  = f2b(w1[i]);
  for (int i = tid; i < 96*864; i += nth) {
    int o = i / 864, k = i % 864;
    int tap = k / 96, c = k % 96;
    w2r[i] = f2b(w2[(o*96 + c)*9 + tap]);   // (O,C,3,3) -> [o][tap*96+c]
  }
}

// =====================================================================
// layout transform: x NCHW fp32 -> xt NHWC bf16, coalesced both sides
// block = (b, i, 64-px j-tile); grid 8*192*3 = 4608
// =====================================================================
__global__ __launch_bounds__(256) void k_xt(
    const float* __restrict__ x, unsigned short* __restrict__ xt) {
  __shared__ __align__(16) float tile[96*65];  // 24960 B, pad 65 vs bank conflicts
  int blk = blockIdx.x;
  int b = blk / 576, rem = blk % 576;
  int i = rem / 3, j0 = (rem % 3) * 64;
  int tid = threadIdx.x;
  const float* xb = x + (size_t)b*96*HW + (size_t)i*WWID + j0;

  for (int f = tid; f < 1536; f += 256) {      // 96 c x 16 float4
    int c = f >> 4, q = f & 15;
    *(floatx4*)&tile[c*65 + 4*q] = *(const floatx4*)&xb[(size_t)c*HW + 4*q];
  }
  __syncthreads();
  unsigned short* xtb = xt + ((size_t)b*HW + (size_t)i*WWID + j0) * 96;
  for (int f = tid; f < 768; f += 256) {       // 64 px x 12 chunks
    int p = f / 12, c0 = (f % 12) * 8;
    short8 o;
    #pragma unroll
    for (int u = 0; u < 8; u++) o[u] = (short)f2b(tile[(c0+u)*65 + p]);
    *(short8*)&xtb[p*96 + c0] = o;
  }
}

// =====================================================================
// window attention: 1 block per 8x8 window, 256 threads (4 waves)
// reads xt NHWC bf16 (coalesced, L3-resident), writes y NHWC bf16
// =====================================================================
#define XW_S 104   // xw [64][104] bf16, alive whole kernel (residual source)
#define QK_S 136   // qk [64][136] bf16 (q cols 0-63, k cols 64-127)
#define VT_S 72    // vt [64][72] bf16: vt[d][t] (V transposed at write time)
#define P_S  72    // p4 [4][64][72]; after-PV overlap: o64 @+0, ybuf @+16384

__global__ __launch_bounds__(256,2) void k_attn(
    const unsigned short* __restrict__ xt, const float* __restrict__ qkv_b,
    const float* __restrict__ out_b, const char* __restrict__ wsr,
    unsigned short* __restrict__ y) {
  __shared__ __align__(16) char smem[76800];
  unsigned short* xw   = (unsigned short*)smem;            // 13312 B
  unsigned short* qk   = (unsigned short*)(smem + 13312);  // 17408 B
  unsigned short* vt   = (unsigned short*)(smem + 30720);  // 9216 B
  unsigned short* p4   = (unsigned short*)(smem + 39936);  // 36864 B
  unsigned short* o64  = (unsigned short*)(smem + 39936);  // 9216 B (post-PV)
  unsigned short* ybuf = (unsigned short*)(smem + 56320);  // 13312 B (post-PV)

  const float* ab = (const float*)(wsr + AB_OFF);
  const unsigned short* qkvw = (const unsigned short*)(wsr + QKVW_OFF);
  const unsigned short* outw = (const unsigned short*)(wsr + OUTW_OFF);

  int blk = blockIdx.x;
  int b = blk / 576, rem = blk % 576;
  int wi = rem / 24, wj = rem % 24;
  int h0 = wi * 8, w0 = wj * 8;
  const unsigned short* xtb = xt + (size_t)b*HW*96;

  int tid = threadIdx.x;
  int wv = tid >> 6, ln = tid & 63;
  int row = ln & 15, kg = ln >> 4;

  const floatx4 zf = {0.f, 0.f, 0.f, 0.f};
  const short8 zs = {0,0,0,0,0,0,0,0};

  // phase 1: xt window -> LDS [t][c] (coalesced 1536B rows)
  for (int f = tid; f < 768; f += 256) {
    int t = f / 12, c0 = (f % 12) * 8;
    int gi = h0 + (t>>3), gj = w0 + (t&7);
    *(short8*)&xw[t*XW_S + c0] =
        *(const short8*)&xtb[((size_t)gi*WWID + gj)*96 + c0];
  }
  __syncthreads();

  // phase 2: qkv GEMM; wave wv covers 16-col tiles jt = 3*wv+n
  floatx4 accq[4][3];
  #pragma unroll
  for (int m = 0; m < 4; m++)
    #pragma unroll
    for (int n = 0; n < 3; n++) accq[m][n] = zf;
  #pragma unroll
  for (int ks = 0; ks < 3; ks++) {
    int c0 = ks*32 + kg*8;
    short8 a[4], bb[3];
    #pragma unroll
    for (int m = 0; m < 4; m++) a[m] = *(const short8*)&xw[(m*16+row)*XW_S + c0];
    #pragma unroll
    for (int n = 0; n < 3; n++) bb[n] = *(const short8*)&qkvw[(wv*48 + n*16 + row)*96 + c0];
    #pragma unroll
    for (int m = 0; m < 4; m++)
      #pragma unroll
      for (int n = 0; n < 3; n++) accq[m][n] = MFMA16x32(a[m], bb[n], accq[m][n]);
  }
  #pragma unroll
  for (int n = 0; n < 3; n++) {
    int jt = 3*wv + n;                 // 16-col tile: jt<4 q, 4..7 k, 8..11 v
    float bj = qkv_b[jt*16 + row];
    #pragma unroll
    for (int m = 0; m < 4; m++) {
      #pragma unroll
      for (int r = 0; r < 4; r++) {
        int t = m*16 + kg*4 + r;
        unsigned short val = f2b(accq[m][n][r] + bj);
        if (jt < 8) qk[t*QK_S + jt*16 + row] = val;          // q,k as [t][j]
        else        vt[((jt-8)*16 + row)*VT_S + t] = val;    // v transposed [d][t]
      }
    }
  }
  __syncthreads();

  // phase 3: scores + softmax + PV, head h = wv
  int h = wv;
  floatx4 sc[4][4];
  {
    short8 qa[4], kb[4];
    if (kg < 2) {   // K dim = 16, zero-pad to 32
      #pragma unroll
      for (int m = 0; m < 4; m++) qa[m] = *(const short8*)&qk[(m*16+row)*QK_S + h*16 + kg*8];
      #pragma unroll
      for (int n = 0; n < 4; n++) kb[n] = *(const short8*)&qk[(n*16+row)*QK_S + 64 + h*16 + kg*8];
    } else {
      #pragma unroll
      for (int m = 0; m < 4; m++) qa[m] = zs;
      #pragma unroll
      for (int n = 0; n < 4; n++) kb[n] = zs;
    }
    #pragma unroll
    for (int m = 0; m < 4; m++)
      #pragma unroll
      for (int n = 0; n < 4; n++) sc[m][n] = MFMA16x32(qa[m], kb[n], zf);
  }
  #pragma unroll
  for (int m = 0; m < 4; m++) {
    #pragma unroll
    for (int r = 0; r < 4; r++) {
      int t = m*16 + kg*4 + r;
      float v[4];
      #pragma unroll
      for (int n = 0; n < 4; n++)
        v[n] = sc[m][n][r]*0.25f + ab[t*64 + n*16 + row];
      float mx = fmaxf(fmaxf(v[0],v[1]), fmaxf(v[2],v[3]));
      #pragma unroll
      for (int d = 1; d < 16; d <<= 1) mx = fmaxf(mx, __shfl_xor(mx, d, 64));
      float sum = 0.f;
      #pragma unroll
      for (int n = 0; n < 4; n++) { v[n] = __expf(v[n]-mx); sum += v[n]; }
      #pragma unroll
      for (int d = 1; d < 16; d <<= 1) sum += __shfl_xor(sum, d, 64);
      float inv = 1.f / sum;
      #pragma unroll
      for (int n = 0; n < 4; n++)
        p4[(h*64 + t)*P_S + n*16 + row] = f2b(v[n]*inv);
    }
  }
  floatx4 ov[4];
  #pragma unroll
  for (int m = 0; m < 4; m++) ov[m] = zf;
  #pragma unroll
  for (int ks = 0; ks < 2; ks++) {
    short8 pa[4];
    #pragma unroll
    for (int m = 0; m < 4; m++)
      pa[m] = *(const short8*)&p4[(h*64 + m*16 + row)*P_S + ks*32 + kg*8];
    short8 vb = *(const short8*)&vt[(h*16 + row)*VT_S + ks*32 + kg*8];
    #pragma unroll
    for (int m = 0; m < 4; m++) ov[m] = MFMA16x32(pa[m], vb, ov[m]);
  }
  __syncthreads();   // all PV reads of p4 done before o64 (aliased) is written

  #pragma unroll
  for (int m = 0; m < 4; m++)
    #pragma unroll
    for (int r = 0; r < 4; r++)
      o64[(m*16 + kg*4 + r)*P_S + h*16 + row] = f2b(ov[m][r]);
  __syncthreads();   // o64 complete (cross-wave read next)

  // phase 4: out projection, wave wv owns t-tile wv
  floatx4 op[6];
  #pragma unroll
  for (int n = 0; n < 6; n++) op[n] = zf;
  #pragma unroll
  for (int ks = 0; ks < 2; ks++) {
    short8 ao = *(const short8*)&o64[(wv*16 + row)*P_S + ks*32 + kg*8];
    #pragma unroll
    for (int n = 0; n < 6; n++) {
      short8 bo = *(const short8*)&outw[(n*16 + row)*64 + ks*32 + kg*8];
      op[n] = MFMA16x32(ao, bo, op[n]);
    }
  }
  #pragma unroll
  for (int n = 0; n < 6; n++) {
    float ob = out_b[n*16 + row];
    #pragma unroll
    for (int r = 0; r < 4; r++) {
      int t = wv*16 + kg*4 + r;
      ybuf[t*XW_S + n*16 + row] = f2b(op[n][r] + ob);
    }
  }
  __syncthreads();

  // phase 5: y = x + o from LDS, write NHWC bf16 coalesced
  for (int f = tid; f < 768; f += 256) {
    int t = f / 12, c0 = (f % 12) * 8;
    short8 yb8 = *(const short8*)&ybuf[t*XW_S + c0];
    short8 xb8 = *(const short8*)&xw[t*XW_S + c0];
    short8 o8;
    #pragma unroll
    for (int u = 0; u < 8; u++)
      o8[u] = (short)f2b(b2f((unsigned short)yb8[u]) + b2f((unsigned short)xb8[u]));
    int gi = h0 + (t>>3), gj = w0 + (t&7);
    *(short8*)&y[((size_t)b*HW + (size_t)gi*WWID + gj)*96 + c0] = o8;
  }
}

// =====================================================================
// conv1 1x1 + leaky: GEMM straight from y NHWC, no LDS.
// =====================================================================
__global__ __launch_bounds__(256,2) void k_conv1(
    const unsigned short* __restrict__ y, const float* __restrict__ b1,
    const char* __restrict__ wsr, unsigned short* __restrict__ h1) {
  const unsigned short* w1b = (const unsigned short*)(wsr + W1_OFF);
  int blk = blockIdx.x;
  int b = blk / 576, rem = blk % 576;
  int i = rem / 3, j0 = (rem % 3) * 64;
  int tid = threadIdx.x;
  int wv = tid >> 6, ln = tid & 63;
  int row = ln & 15, kg = ln >> 4;
  const unsigned short* yb = y + ((size_t)b*HW + (size_t)i*WWID + j0) * 96;
  unsigned short* hb = h1 + ((size_t)b*HW + (size_t)i*WWID + j0) * 96;

  const floatx4 zf = {0.f, 0.f, 0.f, 0.f};
  floatx4 acc[6];
  #pragma unroll
  for (int n = 0; n < 6; n++) acc[n] = zf;
  #pragma unroll
  for (int ks = 0; ks < 3; ks++) {
    int c0 = ks*32 + kg*8;
    short8 a = *(const short8*)&yb[(wv*16 + row)*96 + c0];
    #pragma unroll
    for (int n = 0; n < 6; n++) {
      short8 bw = *(const short8*)&w1b[(n*16 + row)*96 + c0];
      acc[n] = MFMA16x32(a, bw, acc[n]);
    }
  }
  #pragma unroll
  for (int n = 0; n < 6; n++) {
    int o = n*16 + row;
    float bo = b1[o];
    #pragma unroll
    for (int r = 0; r < 4; r++) {
      int p = wv*16 + kg*4 + r;
      float v = acc[n][r] + bo;
      v = v >= 0.f ? v : 0.1f*v;
      hb[p*96 + o] = f2b(v);
    }
  }
}

// =====================================================================
// conv2 3x3 replicate-pad + leaky + residual. Implicit GEMM.
// =====================================================================
__global__ __launch_bounds__(512,4) void k_conv2(
    const unsigned short* __restrict__ h1, const unsigned short* __restrict__ y,
    const float* __restrict__ b2, const char* __restrict__ wsr,
    float* __restrict__ out) {
  __shared__ __align__(16) unsigned short h1t[340*104];   // 10x34 halo x 96ch
  const unsigned short* w2r = (const unsigned short*)(wsr + W2R_OFF);
  int blk = blockIdx.x;
  int b = blk / 144, rem = blk % 144;
  int i0 = (rem / 6) * 8, j0 = (rem % 6) * 32;
  int tid = threadIdx.x;

  for (int idx = tid; idx < 4080; idx += 512) {
    int pix = idx / 12, cc = (idx % 12) * 8;
    int hr = pix / 34, hc = pix % 34;
    int gi = min(max(i0 + hr - 1, 0), 191);
    int gj = min(max(j0 + hc - 1, 0), 191);
    *(short8*)&h1t[pix*104 + cc] =
        *(const short8*)&h1[((size_t)b*HW + (size_t)gi*WWID + gj)*96 + cc];
  }
  __syncthreads();

  int wv = tid >> 6, ln = tid & 63;
  int row = ln & 15, kg = ln >> 4;
  int og = wv >> 2, pg = wv & 3;

  const floatx4 zf = {0.f, 0.f, 0.f, 0.f};
  floatx4 acc[3][4];
  #pragma unroll
  for (int m = 0; m < 3; m++)
    #pragma unroll
    for (int n = 0; n < 4; n++) acc[m][n] = zf;

  for (int s = 0; s < 27; s++) {
    int tap = s / 3, c0 = (s % 3) * 32;
    int di = tap / 3, dj = tap % 3;
    short8 a[3], bb[4];
    #pragma unroll
    for (int m = 0; m < 3; m++)
      a[m] = *(const short8*)&w2r[(og*48 + m*16 + row)*864 + s*32 + kg*8];
    #pragma unroll
    for (int n = 0; n < 4; n++) {
      int p = pg*64 + n*16 + row;
      int pr = p >> 5, pc = p & 31;
      bb[n] = *(const short8*)&h1t[((pr + di)*34 + pc + dj)*104 + c0 + kg*8];
    }
    #pragma unroll
    for (int m = 0; m < 3; m++)
      #pragma unroll
      for (int n = 0; n < 4; n++)
        acc[m][n] = MFMA16x32(a[m], bb[n], acc[m][n]);
  }

  #pragma unroll
  for (int m = 0; m < 3; m++) {
    #pragma unroll
    for (int r = 0; r < 4; r++) {
      int o = og*48 + m*16 + kg*4 + r;
      float bo = b2[o];
      #pragma unroll
      for (int n = 0; n < 4; n++) {
        int p = pg*64 + n*16 + row;
        int pr = p >> 5, pc = p & 31;
        float hv = acc[m][n][r] + bo;
        hv = hv >= 0.f ? hv : 0.1f*hv;
        float yv = b2f(y[((size_t)b*HW + (size_t)(i0+pr)*WWID + j0+pc)*96 + o]);
        out[((size_t)(b*96 + o)*HH + i0 + pr)*WWID + j0 + pc] = yv + hv;
      }
    }
  }
}

// =====================================================================
extern "C" void kernel_launch(void* const* d_in, const int* in_sizes, int n_in,
                              void* d_out, int out_size, void* d_ws, size_t ws_size,
                              hipStream_t stream) {
  const float* x    = (const float*)d_in[0];
  const float* bias = (const float*)d_in[1];
  const float* bpw  = (const float*)d_in[2];
  const float* qkvw = (const float*)d_in[3];
  const float* qkvb = (const float*)d_in[4];
  const float* outw = (const float*)d_in[5];
  const float* outb = (const float*)d_in[6];
  const float* w1   = (const float*)d_in[7];
  const float* b1   = (const float*)d_in[8];
  const float* w2   = (const float*)d_in[9];
  const float* b2   = (const float*)d_in[10];

  char* ws = (char*)d_ws;
  float* out = (float*)d_out;
  unsigned short* y  = (unsigned short*)(ws + Y_OFF);
  unsigned short* h1 = (unsigned short*)(ws + H1_OFF);
  unsigned short* xt = (unsigned short*)(ws + XT_OFF);   // aliases h1 (xt dead before conv1)

  k_prep<<<128, 256, 0, stream>>>(bias, bpw, qkvw, outw, w1, w2, ws);
  k_xt  <<<4608, 256, 0, stream>>>(x, xt);
  k_attn<<<4608, 256, 0, stream>>>(xt, qkvb, outb, ws, y);
  k_conv1<<<4608, 256, 0, stream>>>(y, b1, ws, h1);
  k_conv2<<<1152, 512, 0, stream>>>(h1, y, b2, ws, out);
}

// Round 5
// 250.543 us; speedup vs baseline: 1.3342x; 1.1733x over previous
//
#include <hip/hip_runtime.h>
#include <hip/hip_bf16.h>

typedef __attribute__((ext_vector_type(8))) short short8;
typedef __attribute__((ext_vector_type(4))) short short4v;
typedef __attribute__((ext_vector_type(4))) float floatx4;

#define MFMA16x32(a,b,c) __builtin_amdgcn_mfma_f32_16x16x32_bf16((a),(b),(c),0,0,0)

static __device__ __forceinline__ unsigned short f2b(float f) {
  __hip_bfloat16 h = __float2bfloat16(f);
  return __builtin_bit_cast(unsigned short, h);
}
static __device__ __forceinline__ float b2f(unsigned short u) {
  __hip_bfloat16 h = __builtin_bit_cast(__hip_bfloat16, u);
  return __bfloat162float(h);
}

#define HH 192
#define WWID 192
#define HW (192*192)

// ---- ws layout (bytes) ----
#define Y_OFF    0                      // y = x + attn_out, NHWC bf16: 56623104
#define H1_OFF   56623104               // h1 NHWC bf16 (conv1 out) -- SHARED with xt
#define XT_OFF   56623104               //   xt dead before conv1 writes h1
#define AB_OFF   113246208              // attn_bias f32 PERMUTED [t][row*4+n]
#define QKVW_OFF 113262592              // qkv_w bf16 192*96
#define OUTW_OFF 113299456              // out_w bf16 96*64
#define W1_OFF   113311744              // conv1_w bf16 96*96
#define W2R_OFF  113330176              // conv2_w reordered bf16 96*864

// =====================================================================
// prep: attn bias projection (permuted) + bf16 weight repacks
// =====================================================================
__global__ __launch_bounds__(256) void k_prep(
    const float* __restrict__ bias, const float* __restrict__ bpw,
    const float* __restrict__ qkv_w, const float* __restrict__ out_w,
    const float* __restrict__ w1, const float* __restrict__ w2,
    char* __restrict__ ws) {
  int tid = blockIdx.x * blockDim.x + threadIdx.x;
  int nth = gridDim.x * blockDim.x;
  float* ab = (float*)(ws + AB_OFF);
  unsigned short* qkvw = (unsigned short*)(ws + QKVW_OFF);
  unsigned short* outw = (unsigned short*)(ws + OUTW_OFF);
  unsigned short* w1b  = (unsigned short*)(ws + W1_OFF);
  unsigned short* w2r  = (unsigned short*)(ws + W2R_OFF);

  for (int i = tid; i < 4096; i += nth) {
    float s = 0.f;
    #pragma unroll 8
    for (int k = 0; k < 64; k++) s += bias[k] * bpw[i*64 + k];
    int c = i & 63;                       // col = n*16 + row
    ab[(i & ~63) + ((c & 15) << 2) + (c >> 4)] = s;   // [t][row*4 + n]
  }
  for (int i = tid; i < 192*96; i += nth) qkvw[i] = f2b(qkv_w[i]);
  for (int i = tid; i < 96*64;  i += nth) outw[i] = f2b(out_w[i]);
  for (int i = tid; i < 96*96;  i += nth) w1b[i]  = f2b(w1[i]);
  for (int i = tid; i < 96*864; i += nth) {
    int o = i / 864, k = i % 864;
    int tap = k / 96, c = k % 96;
    w2r[i] = f2b(w2[(o*96 + c)*9 + tap]);   // (O,C,3,3) -> [o][tap*96+c]
  }
}

// =====================================================================
// layout transform: x NCHW fp32 -> xt NHWC bf16, coalesced both sides
// =====================================================================
__global__ __launch_bounds__(256) void k_xt(
    const float* __restrict__ x, unsigned short* __restrict__ xt) {
  __shared__ __align__(16) float tile[96*65];
  int blk = blockIdx.x;
  int b = blk / 576, rem = blk % 576;
  int i = rem / 3, j0 = (rem % 3) * 64;
  int tid = threadIdx.x;
  const float* xb = x + (size_t)b*96*HW + (size_t)i*WWID + j0;

  for (int f = tid; f < 1536; f += 256) {
    int c = f >> 4, q = f & 15;
    *(floatx4*)&tile[c*65 + 4*q] = *(const floatx4*)&xb[(size_t)c*HW + 4*q];
  }
  __syncthreads();
  unsigned short* xtb = xt + ((size_t)b*HW + (size_t)i*WWID + j0) * 96;
  for (int f = tid; f < 768; f += 256) {
    int p = f / 12, c0 = (f % 12) * 8;
    short8 o;
    #pragma unroll
    for (int u = 0; u < 8; u++) o[u] = (short)f2b(tile[(c0+u)*65 + p]);
    *(short8*)&xtb[p*96 + c0] = o;
  }
}

// =====================================================================
// window attention: 1 block per 8x8 window, 4 waves (wave = head).
// LDS 33792B -> 4 blocks/CU. 2 barriers total.
//   vt  [64][72] u16 @0      (V transposed [d][t]; per-wave rows)
//   qkw 4 x 6144B @9216      (per wave: q [64][24], k [64][24]; pchunk [64][40] aliases)
//   o64 [64][72] u16 @0      (aliases vt after barrier B1)
// =====================================================================
__global__ __launch_bounds__(256,4) void k_attn(
    const unsigned short* __restrict__ xt, const float* __restrict__ qkv_b,
    const float* __restrict__ out_b, const char* __restrict__ wsr,
    unsigned short* __restrict__ y) {
  __shared__ __align__(16) char smem[33792];
  unsigned short* vt  = (unsigned short*)smem;
  unsigned short* qkw = (unsigned short*)(smem + 9216);
  unsigned short* o64 = (unsigned short*)smem;          // alias vt after B1

  const float* ab = (const float*)(wsr + AB_OFF);
  const unsigned short* qkvw = (const unsigned short*)(wsr + QKVW_OFF);
  const unsigned short* outw = (const unsigned short*)(wsr + OUTW_OFF);

  int blk = blockIdx.x;
  int b = blk / 576, rem = blk % 576;
  int wi = rem / 24, wj = rem % 24;
  int h0 = wi * 8, w0 = wj * 8;
  const unsigned short* xtw = xt + (size_t)b*HW*96;
  unsigned short* yw = y + (size_t)b*HW*96;

  int tid = threadIdx.x;
  int h = tid >> 6, ln = tid & 63;
  int row = ln & 15, kg = ln >> 4;

  unsigned short* qh = qkw + h*3072;    // [64][24] u16
  unsigned short* kh = qh + 1536;       // [64][24] u16
  unsigned short* pch = qh;             // pchunk [64][40] aliases q+k (wave-local)

  const floatx4 zf = {0.f, 0.f, 0.f, 0.f};
  const short8 zs = {0,0,0,0,0,0,0,0};

  // ---- phase 2: qkv GEMM, A straight from global xt; wave h owns head h ----
  floatx4 accq[4][3];
  #pragma unroll
  for (int m = 0; m < 4; m++)
    #pragma unroll
    for (int n = 0; n < 3; n++) accq[m][n] = zf;
  #pragma unroll
  for (int ks = 0; ks < 3; ks++) {
    int c0 = ks*32 + kg*8;
    short8 a[4], bb[3];
    #pragma unroll
    for (int m = 0; m < 4; m++) {
      int t = m*16 + row;
      a[m] = *(const short8*)&xtw[((size_t)((h0 + (t>>3))*WWID + w0 + (t&7)))*96 + c0];
    }
    #pragma unroll
    for (int n = 0; n < 3; n++)   // jt = n*4 + h  (q_h, k_h, v_h)
      bb[n] = *(const short8*)&qkvw[((n*4 + h)*16 + row)*96 + c0];
    #pragma unroll
    for (int m = 0; m < 4; m++)
      #pragma unroll
      for (int n = 0; n < 3; n++) accq[m][n] = MFMA16x32(a[m], bb[n], accq[m][n]);
  }
  float qb0 = qkv_b[h*16 + row], qb1 = qkv_b[64 + h*16 + row], qb2 = qkv_b[128 + h*16 + row];
  #pragma unroll
  for (int m = 0; m < 4; m++) {
    #pragma unroll
    for (int r = 0; r < 4; r++) {
      int t = m*16 + kg*4 + r;
      qh[t*24 + row] = f2b(accq[m][0][r] + qb0);
      kh[t*24 + row] = f2b(accq[m][1][r] + qb1);
    }
    short4v vv;
    #pragma unroll
    for (int r = 0; r < 4; r++) vv[r] = (short)f2b(accq[m][2][r] + qb2);
    *(short4v*)&vt[(h*16 + row)*72 + m*16 + kg*4] = vv;   // vt[d][t] packed b64
  }
  asm volatile("" ::: "memory");

  // ---- phase 3: scores (K=16 zero-padded) + exp-softmax (no max: |S|<1) ----
  short8 kb[4];
  #pragma unroll
  for (int n = 0; n < 4; n++)
    kb[n] = (kg < 2) ? *(const short8*)&kh[(n*16 + row)*24 + kg*8] : zs;
  unsigned pw[4][4][2];
  float inv[4][4];
  #pragma unroll
  for (int m = 0; m < 4; m++) {
    short8 qa = (kg < 2) ? *(const short8*)&qh[(m*16 + row)*24 + kg*8] : zs;
    floatx4 sc[4];
    #pragma unroll
    for (int n = 0; n < 4; n++) sc[n] = MFMA16x32(qa, kb[n], zf);
    #pragma unroll
    for (int r = 0; r < 4; r++) {
      int t = m*16 + kg*4 + r;
      floatx4 abv = *(const floatx4*)&ab[t*64 + row*4];
      float e0 = __expf(sc[0][r]*0.25f + abv[0]);
      float e1 = __expf(sc[1][r]*0.25f + abv[1]);
      float e2 = __expf(sc[2][r]*0.25f + abv[2]);
      float e3 = __expf(sc[3][r]*0.25f + abv[3]);
      float s = (e0 + e1) + (e2 + e3);
      #pragma unroll
      for (int d = 1; d < 16; d <<= 1) s += __shfl_xor(s, d, 64);
      inv[m][r] = 1.0f / s;
      pw[m][r][0] = (unsigned)f2b(e0) | ((unsigned)f2b(e1) << 16);
      pw[m][r][1] = (unsigned)f2b(e2) | ((unsigned)f2b(e3) << 16);
    }
  }

  // ---- PV in two 32-col chunks through wave-local pchunk ----
  floatx4 ov[4];
  #pragma unroll
  for (int m = 0; m < 4; m++) ov[m] = zf;
  #pragma unroll
  for (int ksk = 0; ksk < 2; ksk++) {
    asm volatile("" ::: "memory");
    #pragma unroll
    for (int m = 0; m < 4; m++)
      #pragma unroll
      for (int r = 0; r < 4; r++) {
        int t = m*16 + kg*4 + r;
        unsigned w = pw[m][r][ksk];
        pch[t*40 + row]      = (unsigned short)w;
        pch[t*40 + 16 + row] = (unsigned short)(w >> 16);
      }
    asm volatile("" ::: "memory");
    short8 vb = *(const short8*)&vt[(h*16 + row)*72 + ksk*32 + kg*8];
    #pragma unroll
    for (int m = 0; m < 4; m++) {
      short8 pa = *(const short8*)&pch[(m*16 + row)*40 + kg*8];
      ov[m] = MFMA16x32(pa, vb, ov[m]);
    }
  }
  __syncthreads();   // B1: all PV reads of vt/pchunk done; o64 may alias vt

  #pragma unroll
  for (int m = 0; m < 4; m++)
    #pragma unroll
    for (int r = 0; r < 4; r++)
      o64[(m*16 + kg*4 + r)*72 + h*16 + row] = f2b(ov[m][r] * inv[m][r]);
  __syncthreads();   // B2: o64 complete (cross-wave)

  // ---- phase 4: out projection; wave h owns t-rows h*16.. ----
  floatx4 op[6];
  #pragma unroll
  for (int n = 0; n < 6; n++) op[n] = zf;
  #pragma unroll
  for (int ks = 0; ks < 2; ks++) {
    short8 ao = *(const short8*)&o64[(h*16 + row)*72 + ks*32 + kg*8];
    #pragma unroll
    for (int n = 0; n < 6; n++) {
      short8 bo = *(const short8*)&outw[(n*16 + row)*64 + ks*32 + kg*8];
      op[n] = MFMA16x32(ao, bo, op[n]);
    }
  }

  // ---- phase 5: y = x + o, direct global write (residual re-read from xt) ----
  #pragma unroll
  for (int n = 0; n < 6; n++) {
    int o = n*16 + row;
    float ob = out_b[o];
    #pragma unroll
    for (int r = 0; r < 4; r++) {
      int t = h*16 + kg*4 + r;
      int gi = h0 + (t>>3), gj = w0 + (t&7);
      size_t gx = ((size_t)(gi*WWID + gj))*96 + o;
      yw[gx] = f2b(op[n][r] + ob + b2f(xtw[gx]));
    }
  }
}

// =====================================================================
// conv1 1x1 + leaky: GEMM straight from y NHWC, no LDS.
// =====================================================================
__global__ __launch_bounds__(256,2) void k_conv1(
    const unsigned short* __restrict__ y, const float* __restrict__ b1,
    const char* __restrict__ wsr, unsigned short* __restrict__ h1) {
  const unsigned short* w1b = (const unsigned short*)(wsr + W1_OFF);
  int blk = blockIdx.x;
  int b = blk / 576, rem = blk % 576;
  int i = rem / 3, j0 = (rem % 3) * 64;
  int tid = threadIdx.x;
  int wv = tid >> 6, ln = tid & 63;
  int row = ln & 15, kg = ln >> 4;
  const unsigned short* yb = y + ((size_t)b*HW + (size_t)i*WWID + j0) * 96;
  unsigned short* hb = h1 + ((size_t)b*HW + (size_t)i*WWID + j0) * 96;

  const floatx4 zf = {0.f, 0.f, 0.f, 0.f};
  floatx4 acc[6];
  #pragma unroll
  for (int n = 0; n < 6; n++) acc[n] = zf;
  #pragma unroll
  for (int ks = 0; ks < 3; ks++) {
    int c0 = ks*32 + kg*8;
    short8 a = *(const short8*)&yb[(wv*16 + row)*96 + c0];
    #pragma unroll
    for (int n = 0; n < 6; n++) {
      short8 bw = *(const short8*)&w1b[(n*16 + row)*96 + c0];
      acc[n] = MFMA16x32(a, bw, acc[n]);
    }
  }
  #pragma unroll
  for (int n = 0; n < 6; n++) {
    int o = n*16 + row;
    float bo = b1[o];
    #pragma unroll
    for (int r = 0; r < 4; r++) {
      int p = wv*16 + kg*4 + r;
      float v = acc[n][r] + bo;
      v = v >= 0.f ? v : 0.1f*v;
      hb[p*96 + o] = f2b(v);
    }
  }
}

// =====================================================================
// conv2 3x3 replicate-pad + leaky + residual. Implicit GEMM.
// =====================================================================
__global__ __launch_bounds__(512,4) void k_conv2(
    const unsigned short* __restrict__ h1, const unsigned short* __restrict__ y,
    const float* __restrict__ b2, const char* __restrict__ wsr,
    float* __restrict__ out) {
  __shared__ __align__(16) unsigned short h1t[340*104];   // 10x34 halo x 96ch
  const unsigned short* w2r = (const unsigned short*)(wsr + W2R_OFF);
  int blk = blockIdx.x;
  int b = blk / 144, rem = blk % 144;
  int i0 = (rem / 6) * 8, j0 = (rem % 6) * 32;
  int tid = threadIdx.x;

  for (int idx = tid; idx < 4080; idx += 512) {
    int pix = idx / 12, cc = (idx % 12) * 8;
    int hr = pix / 34, hc = pix % 34;
    int gi = min(max(i0 + hr - 1, 0), 191);
    int gj = min(max(j0 + hc - 1, 0), 191);
    *(short8*)&h1t[pix*104 + cc] =
        *(const short8*)&h1[((size_t)b*HW + (size_t)gi*WWID + gj)*96 + cc];
  }
  __syncthreads();

  int wv = tid >> 6, ln = tid & 63;
  int row = ln & 15, kg = ln >> 4;
  int og = wv >> 2, pg = wv & 3;

  const floatx4 zf = {0.f, 0.f, 0.f, 0.f};
  floatx4 acc[3][4];
  #pragma unroll
  for (int m = 0; m < 3; m++)
    #pragma unroll
    for (int n = 0; n < 4; n++) acc[m][n] = zf;

  for (int s = 0; s < 27; s++) {
    int tap = s / 3, c0 = (s % 3) * 32;
    int di = tap / 3, dj = tap % 3;
    short8 a[3], bb[4];
    #pragma unroll
    for (int m = 0; m < 3; m++)
      a[m] = *(const short8*)&w2r[(og*48 + m*16 + row)*864 + s*32 + kg*8];
    #pragma unroll
    for (int n = 0; n < 4; n++) {
      int p = pg*64 + n*16 + row;
      int pr = p >> 5, pc = p & 31;
      bb[n] = *(const short8*)&h1t[((pr + di)*34 + pc + dj)*104 + c0 + kg*8];
    }
    #pragma unroll
    for (int m = 0; m < 3; m++)
      #pragma unroll
      for (int n = 0; n < 4; n++)
        acc[m][n] = MFMA16x32(a[m], bb[n], acc[m][n]);
  }

  #pragma unroll
  for (int m = 0; m < 3; m++) {
    #pragma unroll
    for (int r = 0; r < 4; r++) {
      int o = og*48 + m*16 + kg*4 + r;
      float bo = b2[o];
      #pragma unroll
      for (int n = 0; n < 4; n++) {
        int p = pg*64 + n*16 + row;
        int pr = p >> 5, pc = p & 31;
        float hv = acc[m][n][r] + bo;
        hv = hv >= 0.f ? hv : 0.1f*hv;
        float yv = b2f(y[((size_t)b*HW + (size_t)(i0+pr)*WWID + j0+pc)*96 + o]);
        out[((size_t)(b*96 + o)*HH + i0 + pr)*WWID + j0 + pc] = yv + hv;
      }
    }
  }
}

// =====================================================================
extern "C" void kernel_launch(void* const* d_in, const int* in_sizes, int n_in,
                              void* d_out, int out_size, void* d_ws, size_t ws_size,
                              hipStream_t stream) {
  const float* x    = (const float*)d_in[0];
  const float* bias = (const float*)d_in[1];
  const float* bpw  = (const float*)d_in[2];
  const float* qkvw = (const float*)d_in[3];
  const float* qkvb = (const float*)d_in[4];
  const float* outw = (const float*)d_in[5];
  const float* outb = (const float*)d_in[6];
  const float* w1   = (const float*)d_in[7];
  const float* b1   = (const float*)d_in[8];
  const float* w2   = (const float*)d_in[9];
  const float* b2   = (const float*)d_in[10];

  char* ws = (char*)d_ws;
  float* out = (float*)d_out;
  unsigned short* y  = (unsigned short*)(ws + Y_OFF);
  unsigned short* h1 = (unsigned short*)(ws + H1_OFF);
  unsigned short* xt = (unsigned short*)(ws + XT_OFF);

  k_prep<<<128, 256, 0, stream>>>(bias, bpw, qkvw, outw, w1, w2, ws);
  k_xt  <<<4608, 256, 0, stream>>>(x, xt);
  k_attn<<<4608, 256, 0, stream>>>(xt, qkvb, outb, ws, y);
  k_conv1<<<4608, 256, 0, stream>>>(y, b1, ws, h1);
  k_conv2<<<1152, 512, 0, stream>>>(h1, y, b2, ws, out);
}